// Round 9
// baseline (441.046 us; speedup 1.0000x reference)
//
#include <hip/hip_runtime.h>
#include <hip/hip_bf16.h>
#include <stdint.h>

// ---------------------------------------------------------------------------
// TensorizedGRU: m[b,l] = sum_{j,k} s[b,j] x[b,k] W[l,j,k]  (l in [0,256): W1||W2)
// R18 = R16 gemm re-decomposed to 8 waves/block (512 thr), SAME tile/grid:
//  - R17 double-null: setprio dead, prep-rewrite dead (residual ~122us fixed).
//  - Surviving model: wave-chunk serial time ~1260cyc vs ~650 ideal; the gap
//    is per-wave latency stall, unfillable at 2 waves/SIMD (grid 512 x 4-wave
//    blocks = 8 waves/CU). R10's 4-waves/SIMD test was confounded (cross-
//    block Wt re-read -> FETCH x1.9 + f16 cvt). This one keeps every memory
//    invariant: same 128x128 block tile, same grid 512, same Mpart, same Wt
//    walk; wave (wr,wc)=(w>>2,w&3) owns a 64x32 sub-tile (mf=4, nf=2).
//  - Wt frag pairs are read by the two wr-waves of the same block (adjacent
//    in time, same XCD) -> 2nd read is L1/L2-hit, FETCH unchanged.
//  - Regs: racc 32 + a 32 + buf 32 + sv 16 ~ 120; __launch_bounds__(512,4)
//    -> VGPR<=128 -> 2 blocks/CU = 16 waves/CU = 4/SIMD (double today's TLP).
// ws layout:
//   Wt   bf16 [256][65536]  @ 0          (33,554,432 B)  fragment-ordered
//   x_bf bf16 [4096][256]   @ 32MiB+2MiB ( 2,097,152 B)
//   Mpart f32 [8][4096][256]@ +2MiB      (33,554,432 B)
// ---------------------------------------------------------------------------

typedef short bf8 __attribute__((ext_vector_type(8)));   // 8 bf16 = 4 VGPRs
typedef float f32x4 __attribute__((ext_vector_type(4)));

static constexpr size_t WT_OFF  = 0;
static constexpr size_t XBF_OFF = 33554432 + 2097152;
static constexpr size_t MP_OFF  = XBF_OFF + 2097152;

// round-to-nearest-even f32 -> bf16 (finite inputs only)
__device__ __forceinline__ unsigned f2bf(float f) {
    unsigned u = __builtin_bit_cast(unsigned, f);
    return (u + 0x7fffu + ((u >> 16) & 1u)) >> 16;
}
__device__ __forceinline__ unsigned pack2bf(float a, float b) {
    return f2bf(a) | (f2bf(b) << 16);
}

// ---------------- prep: tiled transpose via LDS (coalesced both sides) -----
// (unchanged from R17; Wt layout byte-identical to R12/R16)
__global__ void prep_wx(const float* __restrict__ W1, const float* __restrict__ W2,
                        const float* __restrict__ in0, const float* __restrict__ in1,
                        uint4* __restrict__ Wt, unsigned* __restrict__ x_bf) {
    int bx = blockIdx.x;
    if (bx < 2048) {
        const int tid = threadIdx.x;
        const int n16 = bx >> 7;
        const int g   = bx & 127;
        __shared__ __align__(16) unsigned short lds[16 * 512];   // 16 KiB
        const float* base = (n16 < 8)
            ? (W1 + ((size_t)(n16 * 16) << 16))
            : (W2 + ((size_t)((n16 - 8) * 16) << 16));
        // phase 1: 16 rows x 512 f32 -> bf16 -> swizzled LDS
        #pragma unroll
        for (int t = 0; t < 8; ++t) {
            int idx = t * 256 + tid;
            int r  = idx >> 7;            // 0..15
            int c4 = idx & 127;           // 0..127 (float4 units)
            float4 v = *(const float4*)(base + ((size_t)r << 16) + g * 512 + c4 * 4);
            uint2 o;
            o.x = pack2bf(v.x, v.y);
            o.y = pack2bf(v.z, v.w);
            unsigned byte = (unsigned)(r * 1024 + c4 * 8) ^ (unsigned)((r & 7) << 4);
            *(uint2*)((char*)lds + byte) = o;
        }
        __syncthreads();
        // phase 2: gather frags from LDS, stream 16KB contiguous to Wt
        uint4* outp = Wt + (size_t)(n16 * 1024 + g * 8) * 2 * 64;
        #pragma unroll
        for (int t = 0; t < 4; ++t) {
            int idx  = t * 256 + tid;
            int fl   = idx >> 6;          // 0..15 = kl*2 + kst
            int lane = idx & 63;
            int r = lane & 15;
            int k = (fl >> 1) * 64 + (fl & 1) * 32 + (lane >> 4) * 8;
            unsigned byte = (unsigned)(r * 1024 + k * 2) ^ (unsigned)((r & 7) << 4);
            outp[fl * 64 + lane] = *(const uint4*)((const char*)lds + byte);
        }
    } else {
        unsigned v = (bx - 2048) * 256 + threadIdx.x; // 262,144 units of 4 elems
        unsigned b = v >> 6;
        unsigned j4 = (v & 63u) * 4u;
        const float* src = (j4 < 128) ? (in0 + (size_t)b * 128 + j4)
                                      : (in1 + (size_t)b * 128 + (j4 - 128));
        float4 a = *(const float4*)src;
        uint2 o;
        o.x = pack2bf(a.x, a.y);
        o.y = pack2bf(a.z, a.w);
        ((uint2*)x_bf)[v] = o;
    }
}

// ---------------- main GEMM: 128x128 tile, split-K=8, barrier-free ----------
// grid 512: ks = bx&7 (XCD-pinned), nt = (bx>>3)&1, mt = bx>>4 (0..31).
// block 512 = 8 waves; wave (wr,wc)=(w>>2,w&3) owns rows [wr*64,+64) x
// cols [wc*32,+32) of the 128x128 tile. 2 blocks/CU -> 4 waves/SIMD.
__launch_bounds__(512, 4)
__global__ void gemm_p(const unsigned char* __restrict__ Wt,
                       const float* __restrict__ st0, const float* __restrict__ st1,
                       const __hip_bfloat16* __restrict__ x_bf,
                       float* __restrict__ Mpart) {
    const int bx = blockIdx.x;
    const int ks = bx & 7;                  // split-K slice, pinned per XCD
    const int nt = (bx >> 3) & 1;
    const int mt = bx >> 4;
    const int b0 = mt << 7, n0 = nt << 7;
    const int tid  = threadIdx.x;
    const int lane = tid & 63, wave = tid >> 6;   // wave 0..7
    const int wr = wave >> 2, wc = wave & 3;
    const int l15 = lane & 15, l4 = lane >> 4;
    const int b0r = b0 + wr * 64;

    // s tile: [32 j][132 r] f32 (pad to 132 -> broadcast-clean)
    __shared__ __align__(16) float Sl[32 * 132];
    for (int idx = tid; idx < 4096; idx += 512) {
        int r = idx >> 5, j = idx & 31;
        int jg = ks * 32 + j;
        float v = (jg < 128) ? st0[(size_t)(b0 + r) * 128 + jg]
                             : st1[(size_t)(b0 + r) * 128 + (jg - 128)];
        Sl[j * 132 + r] = v;
    }
    __syncthreads();                        // the ONLY barrier

    // Wave-uniform Wt slice bases in SGPRs: n16(nf) = nt*8 + wc*2 + nf.
    const int n16_0 = __builtin_amdgcn_readfirstlane(nt * 8 + wc * 2 + 0);
    const int n16_1 = __builtin_amdgcn_readfirstlane(nt * 8 + wc * 2 + 1);
    const unsigned char* wb0 = Wt + ((size_t)n16_0 << 21);
    const unsigned char* wb1 = Wt + ((size_t)n16_1 << 21);

    f32x4 racc[4][2];
    #pragma unroll
    for (int mf = 0; mf < 4; ++mf)
        #pragma unroll
        for (int nf = 0; nf < 2; ++nf)
            racc[mf][nf] = (f32x4){0.f, 0.f, 0.f, 0.f};
    const f32x4 zacc = (f32x4){0.f, 0.f, 0.f, 0.f};

    bf8 a[4][2];                            // x A-frags, reloaded per quadrant
    bf8 buf[2][2][2];                       // [ping][nf][kst] B-frags

    // Running within-slice byte offset: vo(q,j) = lane*16 + ks*262144 + q*2048
    //                                           + j*8192   (kst*1024 in imm)
    unsigned vo = (unsigned)lane * 16u + (unsigned)ks * 262144u;

    for (int q = 0; q < 4; ++q) {
        // A-frags for this x-quadrant (x_bf row-major, L2-resident)
        #pragma unroll
        for (int mf = 0; mf < 4; ++mf) {
            const __hip_bfloat16* xp =
                x_bf + (size_t)((b0r + mf * 16 + l15) * 256 + q * 64 + l4 * 8);
            a[mf][0] = *(const bf8*)(xp);
            a[mf][1] = *(const bf8*)(xp + 32);
        }
        // peel j=0 B-frags (one exposed latency per 32 chunks)
        buf[0][0][0] = *(const bf8*)(wb0 + vo);
        buf[0][0][1] = *(const bf8*)(wb0 + vo + 1024);
        buf[0][1][0] = *(const bf8*)(wb1 + vo);
        buf[0][1][1] = *(const bf8*)(wb1 + vo + 1024);
        vo += 8192;                          // -> prefetch target j=1

        const float* svp = Sl + wr * 64 + l4 * 4;   // s row ptr, +132/chunk

        for (int jb = 0; jb < 4; ++jb) {
            #pragma unroll
            for (int jj = 0; jj < 8; ++jj) {
                const int pp = jj & 1;       // compile-time ping-pong
                // prefetch next chunk's B-frags (last chunk of q prefetches
                // 2KB past the j-range: lands in valid ws, overwritten unused)
                buf[pp ^ 1][0][0] = *(const bf8*)(wb0 + vo);
                buf[pp ^ 1][0][1] = *(const bf8*)(wb0 + vo + 1024);
                buf[pp ^ 1][1][0] = *(const bf8*)(wb1 + vo);
                buf[pp ^ 1][1][1] = *(const bf8*)(wb1 + vo + 1024);
                vo += 8192;
                // s broadcast values for this j (imm-folded mf*64B)
                f32x4 sv[4];
                #pragma unroll
                for (int mf = 0; mf < 4; ++mf)
                    sv[mf] = *(const f32x4*)(svp + mf * 16);
                svp += 132;
                // 16 MFMA + 8 pk-fma, distance-1 pipeline, named regs.
                {
                    f32x4 mA, mB;
#define PAIR_(MF, NF, MD) \
    MD = __builtin_amdgcn_mfma_f32_16x16x32_bf16(a[MF][0], buf[pp][NF][0], zacc, 0, 0, 0); \
    MD = __builtin_amdgcn_mfma_f32_16x16x32_bf16(a[MF][1], buf[pp][NF][1], MD, 0, 0, 0);
#define ACC_(MF, NF, MS) racc[MF][NF] += sv[MF] * MS;
                    PAIR_(0, 0, mA)
                    PAIR_(1, 0, mB)  ACC_(0, 0, mA)
                    PAIR_(2, 0, mA)  ACC_(1, 0, mB)
                    PAIR_(3, 0, mB)  ACC_(2, 0, mA)
                    PAIR_(0, 1, mA)  ACC_(3, 0, mB)
                    PAIR_(1, 1, mB)  ACC_(0, 1, mA)
                    PAIR_(2, 1, mA)  ACC_(1, 1, mB)
                    PAIR_(3, 1, mB)  ACC_(2, 1, mA)
                                     ACC_(3, 1, mB)
#undef PAIR_
#undef ACC_
                }
            }
        }
        vo += 2048 - 33 * 8192;              // rewind to (q+1, j=0)
    }

    // split-K partial stores (regular stores: producer->consumer coherence)
    float* mp = Mpart + ((size_t)ks << 20);
    #pragma unroll
    for (int mf = 0; mf < 4; ++mf)
        #pragma unroll
        for (int nf = 0; nf < 2; ++nf) {
            int b = b0r + mf * 16 + l4 * 4;
            int n = n0 + wc * 32 + nf * 16 + l15;
            #pragma unroll
            for (int r = 0; r < 4; ++r)
                mp[(size_t)(b + r) * 256 + n] = racc[mf][nf][r];
        }
}

// ---------------- epilogue: reduce split-K, s@W3, activations, blend --------
__global__ void epilogue(const float* __restrict__ st0, const float* __restrict__ st1,
                         const float* __restrict__ b1, const float* __restrict__ b2,
                         const float* __restrict__ W3, const float* __restrict__ Mpart,
                         float* __restrict__ out) {
    const int tid = threadIdx.x;
    const int h = tid & 127, rg = tid >> 7;          // rg in {0,1}
    const int bbase = blockIdx.x * 4;                // 4 rows per block
    __shared__ float srow[4][256];
    #pragma unroll
    for (int i = 0; i < 4; ++i) {
        int idx = i * 256 + tid;
        int r = idx >> 8, j = idx & 255;
        float v = (j < 128) ? st0[(size_t)(bbase + r) * 128 + j]
                            : st1[(size_t)(bbase + r) * 128 + (j - 128)];
        srow[r][j] = v;
    }
    __syncthreads();
    float acc0 = 0.f, acc1 = 0.f;
    #pragma unroll 8
    for (int j = 0; j < 256; ++j) {
        float w = W3[j * 128 + h];
        acc0 += srow[rg][j] * w;
        acc1 += srow[rg + 2][j] * w;
    }
    float accs[2] = {acc0, acc1};
    float bb1 = b1[h], bb2 = b2[h];
    #pragma unroll
    for (int i = 0; i < 2; ++i) {
        int b = bbase + rg + i * 2;
        float m1 = 0.f, m2 = 0.f;
        #pragma unroll
        for (int k = 0; k < 8; ++k) {
            m1 += Mpart[((size_t)k << 20) + (size_t)b * 256 + h];
            m2 += Mpart[((size_t)k << 20) + (size_t)b * 256 + 128 + h];
        }
        float u = 1.0f / (1.0f + expf(-(m2 + bb2)));
        float t = tanhf(m1 + bb1);
        out[(size_t)b * 128 + h] = u * t + (1.0f - u) * accs[i];
    }
}

extern "C" void kernel_launch(void* const* d_in, const int* in_sizes, int n_in,
                              void* d_out, int out_size, void* d_ws, size_t ws_size,
                              hipStream_t stream) {
    const float* in0 = (const float*)d_in[0];
    const float* in1 = (const float*)d_in[1];
    const float* st0 = (const float*)d_in[2];
    const float* st1 = (const float*)d_in[3];
    const float* W1  = (const float*)d_in[4];
    const float* b1  = (const float*)d_in[5];
    const float* W2  = (const float*)d_in[6];
    const float* b2  = (const float*)d_in[7];
    const float* W3  = (const float*)d_in[8];
    float* out = (float*)d_out;
    char* ws = (char*)d_ws;

    unsigned char* Wt   = (unsigned char*)(ws + WT_OFF);
    unsigned*      x_bf = (unsigned*)(ws + XBF_OFF);
    float*         Mp   = (float*)(ws + MP_OFF);

    prep_wx<<<3072, 256, 0, stream>>>(W1, W2, in0, in1, (uint4*)Wt, x_bf);
    gemm_p<<<512, 512, 0, stream>>>(Wt, st0, st1, (const __hip_bfloat16*)x_bf, Mp);
    epilogue<<<1024, 256, 0, stream>>>(st0, st1, b1, b2, W3, Mp, out);
}

// Round 10
// 275.910 us; speedup vs baseline: 1.5985x; 1.5985x over previous
//
#include <hip/hip_runtime.h>
#include <hip/hip_bf16.h>
#include <stdint.h>

// ---------------------------------------------------------------------------
// TensorizedGRU: m[b,l] = sum_{j,k} s[b,j] x[b,k] W[l,j,k]  (l in [0,256): W1||W2)
// R19 = R16 gemm re-cut for TLP with ALL traffic invariants held:
//  - R18 post-mortem: __launch_bounds__(512,4) -> allocator budgeted 64 VGPR
//    (8 waves/SIMD assumption) -> total spill (FETCH 675MB, WRITE 424MB).
//    Experiment void. Empirical: only (256,2)->128 cap is safe.
//  - R16 was BOTH grid-limited (512 blocks = 2 blocks/CU) and register-
//    limited (128 arch + 64 AGPR = 192/wave -> 2.6/SIMD unified-file).
//  - Fix: split n, not m/K: grid = ks8 x nt4 x mt32 = 1024; wave owns ONE
//    n16 slice (nf=1, mf=8). Wt frag still read by exactly 32 mt-blocks
//    (FETCH invariant, unlike R10); B-bytes/MFMA stays 128; Mpart/Sl/stores
//    unchanged. Regs: a64 + buf16 + sv32 ~ 112 arch + racc 32 AGPR = 144
//    -> 3 waves/SIMD (4 if allocator squeezes like R10's 64).
//  - Everything else identical to R16/R17 (prep R17, epilogue R17,
//    distance-1 MFMA->fma macro pipeline, 1-chunk B prefetch).
// ws layout:
//   Wt   bf16 [256][65536]  @ 0          (33,554,432 B)  fragment-ordered
//   x_bf bf16 [4096][256]   @ 32MiB+2MiB ( 2,097,152 B)
//   Mpart f32 [8][4096][256]@ +2MiB      (33,554,432 B)
// ---------------------------------------------------------------------------

typedef short bf8 __attribute__((ext_vector_type(8)));   // 8 bf16 = 4 VGPRs
typedef float f32x4 __attribute__((ext_vector_type(4)));

static constexpr size_t WT_OFF  = 0;
static constexpr size_t XBF_OFF = 33554432 + 2097152;
static constexpr size_t MP_OFF  = XBF_OFF + 2097152;

// round-to-nearest-even f32 -> bf16 (finite inputs only)
__device__ __forceinline__ unsigned f2bf(float f) {
    unsigned u = __builtin_bit_cast(unsigned, f);
    return (u + 0x7fffu + ((u >> 16) & 1u)) >> 16;
}
__device__ __forceinline__ unsigned pack2bf(float a, float b) {
    return f2bf(a) | (f2bf(b) << 16);
}

// ---------------- prep: tiled transpose via LDS (coalesced both sides) -----
// (unchanged from R17; Wt layout byte-identical to R12/R16)
__global__ void prep_wx(const float* __restrict__ W1, const float* __restrict__ W2,
                        const float* __restrict__ in0, const float* __restrict__ in1,
                        uint4* __restrict__ Wt, unsigned* __restrict__ x_bf) {
    int bx = blockIdx.x;
    if (bx < 2048) {
        const int tid = threadIdx.x;
        const int n16 = bx >> 7;
        const int g   = bx & 127;
        __shared__ __align__(16) unsigned short lds[16 * 512];   // 16 KiB
        const float* base = (n16 < 8)
            ? (W1 + ((size_t)(n16 * 16) << 16))
            : (W2 + ((size_t)((n16 - 8) * 16) << 16));
        // phase 1: 16 rows x 512 f32 -> bf16 -> swizzled LDS
        #pragma unroll
        for (int t = 0; t < 8; ++t) {
            int idx = t * 256 + tid;
            int r  = idx >> 7;            // 0..15
            int c4 = idx & 127;           // 0..127 (float4 units)
            float4 v = *(const float4*)(base + ((size_t)r << 16) + g * 512 + c4 * 4);
            uint2 o;
            o.x = pack2bf(v.x, v.y);
            o.y = pack2bf(v.z, v.w);
            unsigned byte = (unsigned)(r * 1024 + c4 * 8) ^ (unsigned)((r & 7) << 4);
            *(uint2*)((char*)lds + byte) = o;
        }
        __syncthreads();
        // phase 2: gather frags from LDS, stream 16KB contiguous to Wt
        uint4* outp = Wt + (size_t)(n16 * 1024 + g * 8) * 2 * 64;
        #pragma unroll
        for (int t = 0; t < 4; ++t) {
            int idx  = t * 256 + tid;
            int fl   = idx >> 6;          // 0..15 = kl*2 + kst
            int lane = idx & 63;
            int r = lane & 15;
            int k = (fl >> 1) * 64 + (fl & 1) * 32 + (lane >> 4) * 8;
            unsigned byte = (unsigned)(r * 1024 + k * 2) ^ (unsigned)((r & 7) << 4);
            outp[fl * 64 + lane] = *(const uint4*)((const char*)lds + byte);
        }
    } else {
        unsigned v = (bx - 2048) * 256 + threadIdx.x; // 262,144 units of 4 elems
        unsigned b = v >> 6;
        unsigned j4 = (v & 63u) * 4u;
        const float* src = (j4 < 128) ? (in0 + (size_t)b * 128 + j4)
                                      : (in1 + (size_t)b * 128 + (j4 - 128));
        float4 a = *(const float4*)src;
        uint2 o;
        o.x = pack2bf(a.x, a.y);
        o.y = pack2bf(a.z, a.w);
        ((uint2*)x_bf)[v] = o;
    }
}

// ---------------- main GEMM: 128-row x 64-col tile, split-K=8 ---------------
// grid 1024: ks = bx&7 (XCD-pinned), nt = (bx>>3)&3, mt = bx>>5 (0..31).
// block 256 = 4 waves; wave w owns n16 = nt*4+w (16 n-cols), all 128 m-rows.
__launch_bounds__(256, 2)
__global__ void gemm_p(const unsigned char* __restrict__ Wt,
                       const float* __restrict__ st0, const float* __restrict__ st1,
                       const __hip_bfloat16* __restrict__ x_bf,
                       float* __restrict__ Mpart) {
    const int bx = blockIdx.x;
    const int ks = bx & 7;                  // split-K slice, pinned per XCD
    const int nt = (bx >> 3) & 3;           // 0..3 (64 n-cols each)
    const int mt = bx >> 5;                 // 0..31
    const int b0 = mt << 7, n0 = nt << 6;
    const int tid  = threadIdx.x;
    const int lane = tid & 63, wave = tid >> 6;
    const int l15 = lane & 15, l4 = lane >> 4;

    // s tile: [32 j][132 r] f32 (pad to 132 -> broadcast-clean)
    __shared__ __align__(16) float Sl[32 * 132];
    for (int idx = tid; idx < 4096; idx += 256) {
        int r = idx >> 5, j = idx & 31;
        int jg = ks * 32 + j;
        float v = (jg < 128) ? st0[(size_t)(b0 + r) * 128 + jg]
                             : st1[(size_t)(b0 + r) * 128 + (jg - 128)];
        Sl[j * 132 + r] = v;
    }
    __syncthreads();                        // the ONLY barrier

    // Wave-uniform Wt slice base in SGPR: n16 = nt*4 + wave (one slice/wave).
    const int n16 = __builtin_amdgcn_readfirstlane(nt * 4 + wave);
    const unsigned char* wb = Wt + ((size_t)n16 << 21);

    f32x4 racc[8];
    #pragma unroll
    for (int mf = 0; mf < 8; ++mf)
        racc[mf] = (f32x4){0.f, 0.f, 0.f, 0.f};
    const f32x4 zacc = (f32x4){0.f, 0.f, 0.f, 0.f};

    bf8 a[8][2];                            // x A-frags, reloaded per quadrant
    bf8 buf[2][2];                          // [ping][kst] B-frags

    // Running within-slice byte offset: vo(q,j) = lane*16 + ks*262144 + q*2048
    //                                           + j*8192   (kst*1024 in imm)
    unsigned vo = (unsigned)lane * 16u + (unsigned)ks * 262144u;

    for (int q = 0; q < 4; ++q) {
        // A-frags for this x-quadrant (x_bf row-major, L2-resident)
        #pragma unroll
        for (int mf = 0; mf < 8; ++mf) {
            const __hip_bfloat16* xp =
                x_bf + (size_t)((b0 + mf * 16 + l15) * 256 + q * 64 + l4 * 8);
            a[mf][0] = *(const bf8*)(xp);
            a[mf][1] = *(const bf8*)(xp + 32);
        }
        // peel j=0 B-frags (one exposed latency per 32 chunks)
        buf[0][0] = *(const bf8*)(wb + vo);
        buf[0][1] = *(const bf8*)(wb + vo + 1024);
        vo += 8192;                          // -> prefetch target j=1

        const float* svp = Sl + l4 * 4;      // s broadcast ptr, +132/chunk

        for (int jb = 0; jb < 4; ++jb) {
            #pragma unroll
            for (int jj = 0; jj < 8; ++jj) {
                const int pp = jj & 1;       // compile-time ping-pong
                // prefetch next chunk's B-frags (last chunk of q prefetches
                // past the j-range: lands in valid ws/gap, discarded)
                buf[pp ^ 1][0] = *(const bf8*)(wb + vo);
                buf[pp ^ 1][1] = *(const bf8*)(wb + vo + 1024);
                vo += 8192;
                // s broadcast values for this j (imm-folded mf*64B)
                f32x4 sv[8];
                #pragma unroll
                for (int mf = 0; mf < 8; ++mf)
                    sv[mf] = *(const f32x4*)(svp + mf * 16);
                svp += 132;
                // 16 MFMA + 8 pk-fma, distance-1 pipeline, named regs.
                {
                    f32x4 mA, mB;
#define PAIR_(MF, MD) \
    MD = __builtin_amdgcn_mfma_f32_16x16x32_bf16(a[MF][0], buf[pp][0], zacc, 0, 0, 0); \
    MD = __builtin_amdgcn_mfma_f32_16x16x32_bf16(a[MF][1], buf[pp][1], MD, 0, 0, 0);
#define ACC_(MF, MS) racc[MF] += sv[MF] * MS;
                    PAIR_(0, mA)
                    PAIR_(1, mB)  ACC_(0, mA)
                    PAIR_(2, mA)  ACC_(1, mB)
                    PAIR_(3, mB)  ACC_(2, mA)
                    PAIR_(4, mA)  ACC_(3, mB)
                    PAIR_(5, mB)  ACC_(4, mA)
                    PAIR_(6, mA)  ACC_(5, mB)
                    PAIR_(7, mB)  ACC_(6, mA)
                                  ACC_(7, mB)
#undef PAIR_
#undef ACC_
                }
            }
        }
        vo += 2048 - 33 * 8192;              // rewind to (q+1, j=0)
    }

    // split-K partial stores (regular stores: producer->consumer coherence)
    float* mp = Mpart + ((size_t)ks << 20);
    const int n = (n16 << 4) + l15;          // = n0 + wave*16 + l15
    #pragma unroll
    for (int mf = 0; mf < 8; ++mf) {
        int b = b0 + mf * 16 + l4 * 4;
        #pragma unroll
        for (int r = 0; r < 4; ++r)
            mp[(size_t)(b + r) * 256 + n] = racc[mf][r];
    }
}

// ---------------- epilogue: reduce split-K, s@W3, activations, blend --------
__global__ void epilogue(const float* __restrict__ st0, const float* __restrict__ st1,
                         const float* __restrict__ b1, const float* __restrict__ b2,
                         const float* __restrict__ W3, const float* __restrict__ Mpart,
                         float* __restrict__ out) {
    const int tid = threadIdx.x;
    const int h = tid & 127, rg = tid >> 7;          // rg in {0,1}
    const int bbase = blockIdx.x * 4;                // 4 rows per block
    __shared__ float srow[4][256];
    #pragma unroll
    for (int i = 0; i < 4; ++i) {
        int idx = i * 256 + tid;
        int r = idx >> 8, j = idx & 255;
        float v = (j < 128) ? st0[(size_t)(bbase + r) * 128 + j]
                            : st1[(size_t)(bbase + r) * 128 + (j - 128)];
        srow[r][j] = v;
    }
    __syncthreads();
    float acc0 = 0.f, acc1 = 0.f;
    #pragma unroll 8
    for (int j = 0; j < 256; ++j) {
        float w = W3[j * 128 + h];
        acc0 += srow[rg][j] * w;
        acc1 += srow[rg + 2][j] * w;
    }
    float accs[2] = {acc0, acc1};
    float bb1 = b1[h], bb2 = b2[h];
    #pragma unroll
    for (int i = 0; i < 2; ++i) {
        int b = bbase + rg + i * 2;
        float m1 = 0.f, m2 = 0.f;
        #pragma unroll
        for (int k = 0; k < 8; ++k) {
            m1 += Mpart[((size_t)k << 20) + (size_t)b * 256 + h];
            m2 += Mpart[((size_t)k << 20) + (size_t)b * 256 + 128 + h];
        }
        float u = 1.0f / (1.0f + expf(-(m2 + bb2)));
        float t = tanhf(m1 + bb1);
        out[(size_t)b * 128 + h] = u * t + (1.0f - u) * accs[i];
    }
}

extern "C" void kernel_launch(void* const* d_in, const int* in_sizes, int n_in,
                              void* d_out, int out_size, void* d_ws, size_t ws_size,
                              hipStream_t stream) {
    const float* in0 = (const float*)d_in[0];
    const float* in1 = (const float*)d_in[1];
    const float* st0 = (const float*)d_in[2];
    const float* st1 = (const float*)d_in[3];
    const float* W1  = (const float*)d_in[4];
    const float* b1  = (const float*)d_in[5];
    const float* W2  = (const float*)d_in[6];
    const float* b2  = (const float*)d_in[7];
    const float* W3  = (const float*)d_in[8];
    float* out = (float*)d_out;
    char* ws = (char*)d_ws;

    unsigned char* Wt   = (unsigned char*)(ws + WT_OFF);
    unsigned*      x_bf = (unsigned*)(ws + XBF_OFF);
    float*         Mp   = (float*)(ws + MP_OFF);

    prep_wx<<<3072, 256, 0, stream>>>(W1, W2, in0, in1, (uint4*)Wt, x_bf);
    gemm_p<<<1024, 256, 0, stream>>>(Wt, st0, st1, (const __hip_bfloat16*)x_bf, Mp);
    epilogue<<<1024, 256, 0, stream>>>(st0, st1, b1, b2, W3, Mp, out);
}